// Round 8
// baseline (66.082 us; speedup 1.0000x reference)
//
#include <hip/hip_runtime.h>
#include <math.h>

// Problem: B=2, C=4, D=H=W=128. ROWS = B*C = 8 independent top-k rows. N = 2,097,152.
#define ROWS 8
#define TPB  256
#define SLACK 17500u       // DKW rank slack for 1/8 sampling (p_fail ~ 3e-16/side/row)
#define SBINS 8192         // sample-hist bins: u >> 17  (v<1 -> bin <= 8128)
#define SSHIFT 17

// ---------------- workspace layout (fast path) ----------------
#define OFF_SAMPLE 4096
#define FIXED_END  (OFF_SAMPLE + ROWS * SBINS * 4)

struct StateS {
    float        Uval[ROWS];    // exact-count threshold (value-space)
    unsigned int bU[ROWS];      // top gap bin index
    unsigned int bL[ROWS];      // bottom gap bin index
    unsigned int cntHi[ROWS];   // exact count of v >= Uval (by the fast predicate)
    double       sumHi[ROWS];   // exact sum  of v >= Uval (same predicate)
};

#if __has_builtin(__builtin_amdgcn_rcpf)
#define RCPF(x) __builtin_amdgcn_rcpf(x)
#else
#define RCPF(x) (1.0f / (x))
#endif

// fast sigmoid diff: d = sigmoid(x) - t using raw v_rcp (err ~1e-5 << 9.5e-3 budget)
__device__ __forceinline__ float sig_d(float x, float t) {
    float e = __expf(-x);
    float s = RCPF(1.0f + e);
    return s - t;
}

__device__ __forceinline__ float sq_err(float x, float t) {   // fallback path
    float s = 1.0f / (1.0f + __expf(-x));
    float d = s - t;
    return d * d;
}

#if __has_builtin(__builtin_amdgcn_global_load_lds)
#define GLDS_OK 1
__device__ __forceinline__ void glds16(const float4* g, float4* l) {
    __builtin_amdgcn_global_load_lds(
        (const __attribute__((address_space(1))) unsigned int*)g,
        (__attribute__((address_space(3))) unsigned int*)l,
        16, 0, 0);
}
#else
#define GLDS_OK 0
#endif

// ---- 1. sample pass: 1/8 of data, hist of float-bits(d^2) >> 17 ----
__global__ __launch_bounds__(TPB) void k_sample(const float4* __restrict__ x4,
                                                const float4* __restrict__ t4,
                                                unsigned int* __restrict__ sampleHist,
                                                int N) {
    __shared__ unsigned int h[SBINS];
    const int row = blockIdx.x >> 5;
    const int blk = blockIdx.x & 31;
    for (int i = threadIdx.x; i < SBINS; i += TPB) h[i] = 0u;
    __syncthreads();
    const float4* xr = x4 + (size_t)row * (N / 4);
    const float4* tr = t4 + (size_t)row * (N / 4);
    const unsigned base = (unsigned)blk * (unsigned)(N / 4 / 32);
    for (unsigned i = threadIdx.x; i < 2048u; i += TPB) {
        float4 xv = xr[base + i];
        float4 tv = tr[base + i];
        const float* xp = &xv.x;
        const float* tp = &tv.x;
#pragma unroll
        for (int j = 0; j < 4; ++j) {
            float d = sig_d(xp[j], tp[j]);
            float v = d * d;
            atomicAdd(&h[__float_as_uint(v) >> SSHIFT], 1u);
        }
    }
    __syncthreads();
    for (int i = threadIdx.x; i < SBINS; i += TPB) {
        unsigned int c = h[i];
        if (c) atomicAdd(&sampleHist[row * SBINS + i], c);
    }
}

// ---- 2. per-row bracket [bL, bU] from sample hist (tree reductions, no LDS atomics) ----
__global__ __launch_bounds__(TPB) void k_range(const unsigned int* __restrict__ sampleHist,
                                               StateS* st, unsigned int n) {
    __shared__ unsigned int ssum[TPB];
    __shared__ int redU[TPB];
    __shared__ int redL[TPB];
    const int row = blockIdx.x;
    const int t   = threadIdx.x;
    const unsigned int* h = sampleHist + row * SBINS;
    const unsigned int kU = (n - SLACK + 7u) / 8u;
    const unsigned int kL = (n + SLACK + 7u) / 8u;

    unsigned int local[32];
    unsigned int ts = 0;
#pragma unroll
    for (int j = 0; j < 32; ++j) { local[j] = h[t * 32 + j]; ts += local[j]; }
    ssum[t] = ts;
    __syncthreads();
    for (int off = 1; off < TPB; off <<= 1) {
        unsigned int v = (t + off < TPB) ? ssum[t + off] : 0u;
        __syncthreads();
        ssum[t] += v;
        __syncthreads();
    }
    unsigned int S = ssum[t] - ts;
    int locU = -1, locL = -1;
    for (int j = 31; j >= 0; --j) {
        S += local[j];
        int b = t * 32 + j;
        if (S >= kU && b > locU) locU = b;
        if (S >= kL && b > locL) locL = b;
    }
    redU[t] = locU;
    redL[t] = locL;
    __syncthreads();
    for (int off = TPB / 2; off > 0; off >>= 1) {
        if (t < off) {
            if (redU[t + off] > redU[t]) redU[t] = redU[t + off];
            if (redL[t + off] > redL[t]) redL[t] = redL[t + off];
        }
        __syncthreads();
    }
    if (t == 0) {
        int bU = redU[0] < 0 ? 0 : redU[0];
        int bL = redL[0] < 0 ? 0 : redL[0];
        st->bU[row] = (unsigned int)bU;
        st->bL[row] = (unsigned int)bL;
        st->Uval[row] = __uint_as_float(((unsigned int)bU + 1u) << SSHIFT);
        st->cntHi[row] = 0u;
        st->sumHi[row] = 0.0;
    }
}

// ---- 3. THE single full pass, v3. R7 lesson: time invariant to HBM-vs-L3 AND to
// VALU load => bound by the VGPR vector-load return path (~12.6 B/cyc/CU, L1/MSHR
// streaming limit). GEMM proves global_load_lds sustains ~4x that. So: stage both
// streams via global_load_lds into wave-private LDS double buffers (no VGPR
// pressure, no barriers), explicit vmcnt pipeline. ----
__global__ __launch_bounds__(TPB) void k_mainsum(const float4* __restrict__ x4,
                                                 const float4* __restrict__ t4,
                                                 StateS* st, int N) {
    const int row   = blockIdx.x >> 8;            // 256 blocks per row
    const int chunk = blockIdx.x & 255;
    const float Uf  = st->Uval[row];
    const float sU  = __builtin_sqrtf(Uf);
    const int tid  = threadIdx.x;
    const float4* xr = x4 + (size_t)row * (N / 4) + (unsigned)chunk * 2048u + tid;
    const float4* tr = t4 + (size_t)row * (N / 4) + (unsigned)chunk * 2048u + tid;

    float acc0 = 0.0f, acc1 = 0.0f;
    unsigned int cntw = 0u;

#if GLDS_OK
    __shared__ float4 stage[4][2][2][64];         // [wave][buf][x/t][lane] = 16 KB
    const int wid  = tid >> 6;
    const int lane = tid & 63;

    // prologue: stage iter 0 into buf 0 (lds dest is wave-uniform; HW adds lane*16)
    glds16(xr, &stage[wid][0][0][0]);
    glds16(tr, &stage[wid][0][1][0]);
#pragma unroll
    for (int i = 0; i < 8; ++i) {
        const int buf = i & 1;
        if (i < 7) {
            glds16(xr + (i + 1) * TPB, &stage[wid][buf ^ 1][0][0]);
            glds16(tr + (i + 1) * TPB, &stage[wid][buf ^ 1][1][0]);
            asm volatile("s_waitcnt vmcnt(2)" ::: "memory");
        } else {
            asm volatile("s_waitcnt vmcnt(0)" ::: "memory");
        }
        float4 xv = stage[wid][buf][0][lane];
        float4 tv = stage[wid][buf][1][lane];
        float d0 = sig_d(xv.x, tv.x);
        float d1 = sig_d(xv.y, tv.y);
        float d2 = sig_d(xv.z, tv.z);
        float d3 = sig_d(xv.w, tv.w);
        bool p0 = fabsf(d0) >= sU;
        bool p1 = fabsf(d1) >= sU;
        bool p2 = fabsf(d2) >= sU;
        bool p3 = fabsf(d3) >= sU;
        float e0 = p0 ? d0 : 0.0f;
        float e1 = p1 ? d1 : 0.0f;
        float e2 = p2 ? d2 : 0.0f;
        float e3 = p3 ? d3 : 0.0f;
        acc0 = fmaf(e0, e0, acc0);
        acc1 = fmaf(e1, e1, acc1);
        acc0 = fmaf(e2, e2, acc0);
        acc1 = fmaf(e3, e3, acc1);
        cntw += (unsigned)__popcll(__ballot(p0));
        cntw += (unsigned)__popcll(__ballot(p1));
        cntw += (unsigned)__popcll(__ballot(p2));
        cntw += (unsigned)__popcll(__ballot(p3));
    }
#else
#pragma unroll
    for (int g = 0; g < 2; ++g) {
        float4 xs[4], tv4[4];
#pragma unroll
        for (int r = 0; r < 4; ++r) xs[r]  = xr[(unsigned)(g * 4 + r) * TPB];
#pragma unroll
        for (int r = 0; r < 4; ++r) tv4[r] = tr[(unsigned)(g * 4 + r) * TPB];
#pragma unroll
        for (int r = 0; r < 4; ++r) {
            float d0 = sig_d(xs[r].x, tv4[r].x);
            float d1 = sig_d(xs[r].y, tv4[r].y);
            float d2 = sig_d(xs[r].z, tv4[r].z);
            float d3 = sig_d(xs[r].w, tv4[r].w);
            bool p0 = fabsf(d0) >= sU, p1 = fabsf(d1) >= sU;
            bool p2 = fabsf(d2) >= sU, p3 = fabsf(d3) >= sU;
            float e0 = p0 ? d0 : 0.0f, e1 = p1 ? d1 : 0.0f;
            float e2 = p2 ? d2 : 0.0f, e3 = p3 ? d3 : 0.0f;
            acc0 = fmaf(e0, e0, acc0); acc1 = fmaf(e1, e1, acc1);
            acc0 = fmaf(e2, e2, acc0); acc1 = fmaf(e3, e3, acc1);
            cntw += (unsigned)__popcll(__ballot(p0));
            cntw += (unsigned)__popcll(__ballot(p1));
            cntw += (unsigned)__popcll(__ballot(p2));
            cntw += (unsigned)__popcll(__ballot(p3));
        }
    }
#endif

    __shared__ double sh[TPB];
    __shared__ unsigned int scW[TPB / 64];
    sh[threadIdx.x] = (double)(acc0 + acc1);
    if ((threadIdx.x & 63u) == 0u) scW[threadIdx.x >> 6] = cntw;
    __syncthreads();
    for (int off = TPB / 2; off > 0; off >>= 1) {
        if (threadIdx.x < off) sh[threadIdx.x] += sh[threadIdx.x + off];
        __syncthreads();
    }
    if (threadIdx.x == 0) {
        unsigned int c = 0u;
#pragma unroll
        for (int w = 0; w < TPB / 64; ++w) c += scW[w];
        atomicAdd(&st->sumHi[row], sh[0]);
        if (c) atomicAdd(&st->cntHi[row], c);
    }
}

// ---- 4. finalize: distribute m = n - cntHi over sample gap bins (top-down) ----
__global__ void k_fin(const StateS* __restrict__ st,
                      const unsigned int* __restrict__ sampleHist,
                      float* __restrict__ out, unsigned int n) {
    __shared__ double rowTot[ROWS];
    const int t = threadIdx.x;
    if (t < ROWS) {
        const int row = t;
        unsigned int cnt = st->cntHi[row];
        unsigned int m = (n > cnt) ? (n - cnt) : 0u;
        double G = 0.0;
        const unsigned int bU = st->bU[row];
        const unsigned int bL = st->bL[row];
        const unsigned int* h = sampleHist + row * SBINS;
        for (unsigned int b = bU; b + 1u > bL && m > 0u; --b) {
            unsigned int avail = 8u * h[b];
            unsigned int take = (avail < m) ? avail : m;
            double mid = (double)__uint_as_float((b << SSHIFT) | (1u << (SSHIFT - 1)));
            G += (double)take * mid;
            m -= take;
            if (b == 0u) break;
        }
        if (m > 0u) {
            double mid = (double)__uint_as_float((bL << SSHIFT) | (1u << (SSHIFT - 1)));
            G += (double)m * mid;
        }
        rowTot[row] = st->sumHi[row] + G;
    }
    __syncthreads();
    if (t == 0) {
        double tot = 0.0;
        for (int r = 0; r < ROWS; ++r) tot += rowTot[r];
        out[0] = (float)(tot / ((double)ROWS * (double)n));
    }
}

// ================= fallback path (R0, proven exact): 3 radix passes + sum =================
#define FBINS 2048
struct SelState {
    unsigned int prefix[ROWS];
    unsigned int krem[ROWS];
    unsigned int tau[ROWS];
    double       sum_gt[ROWS];
};

__global__ void k_init(unsigned int* __restrict__ hist, SelState* st, unsigned int n) {
    int t = threadIdx.x;
    for (int i = t; i < ROWS * FBINS; i += TPB) hist[i] = 0;
    if (t < ROWS) {
        st->prefix[t] = 0u; st->krem[t] = n; st->tau[t] = 0u; st->sum_gt[t] = 0.0;
    }
}

__global__ __launch_bounds__(TPB) void k_hist(const float4* __restrict__ x4,
                                              const float4* __restrict__ t4,
                                              unsigned int* __restrict__ hist,
                                              const SelState* __restrict__ st,
                                              int N, unsigned int himask, int shift,
                                              unsigned int binmask) {
    __shared__ unsigned int lh[FBINS];
    const int row   = blockIdx.x / 128;
    const int chunk = blockIdx.x % 128;
    for (int i = threadIdx.x; i < FBINS; i += TPB) lh[i] = 0u;
    __syncthreads();
    const unsigned int pref = st->prefix[row];
    const int q4 = N / (128 * 4);
    const long long base4 = (long long)row * (N / 4) + (long long)chunk * q4;
    for (int i = threadIdx.x; i < q4; i += TPB) {
        float4 xv = x4[base4 + i];
        float4 tv = t4[base4 + i];
        const float* xp = &xv.x;
        const float* tp = &tv.x;
#pragma unroll
        for (int j = 0; j < 4; ++j) {
            unsigned int u = __float_as_uint(sq_err(xp[j], tp[j]));
            if ((u & himask) == pref) atomicAdd(&lh[(u >> shift) & binmask], 1u);
        }
    }
    __syncthreads();
    for (int i = threadIdx.x; i < FBINS; i += TPB) {
        unsigned int c = lh[i];
        if (c) atomicAdd(&hist[row * FBINS + i], c);
    }
}

__global__ __launch_bounds__(TPB) void k_select(unsigned int* __restrict__ hist,
                                                SelState* st, int shift, int bins, int last) {
    const int row = blockIdx.x;
    const int t   = threadIdx.x;
    const int pb  = bins / TPB;
    unsigned int* h = &hist[row * FBINS];
    const unsigned int k    = st->krem[row];
    const unsigned int pref = st->prefix[row];
    unsigned int local[8];
    unsigned int ts = 0;
    for (int j = 0; j < pb; ++j) { local[j] = h[t * pb + j]; ts += local[j]; }
    __shared__ unsigned int ssum[TPB];
    ssum[t] = ts;
    __syncthreads();
    for (int off = 1; off < TPB; off <<= 1) {
        unsigned int val = (t + off < TPB) ? ssum[t + off] : 0u;
        __syncthreads();
        ssum[t] += val;
        __syncthreads();
    }
    unsigned int above = ssum[t] - ts;
    for (int j = pb - 1; j >= 0; --j) {
        unsigned int c = local[j];
        if (above < k && above + c >= k) {
            unsigned int b  = (unsigned int)(t * pb + j);
            st->krem[row]   = k - above;
            st->prefix[row] = pref | (b << shift);
            if (last) st->tau[row] = pref | (b << shift);
        }
        above += c;
    }
    for (int j = 0; j < pb; ++j) h[t * pb + j] = 0u;
}

__global__ __launch_bounds__(TPB) void k_sum(const float4* __restrict__ x4,
                                             const float4* __restrict__ t4,
                                             SelState* st, int N) {
    const int row   = blockIdx.x / 128;
    const int chunk = blockIdx.x % 128;
    const unsigned int tau = st->tau[row];
    const int q4 = N / (128 * 4);
    const long long base4 = (long long)row * (N / 4) + (long long)chunk * q4;
    double acc = 0.0;
    for (int i = threadIdx.x; i < q4; i += TPB) {
        float4 xv = x4[base4 + i];
        float4 tv = t4[base4 + i];
        const float* xp = &xv.x;
        const float* tp = &tv.x;
#pragma unroll
        for (int j = 0; j < 4; ++j) {
            float v = sq_err(xp[j], tp[j]);
            if (__float_as_uint(v) > tau) acc += (double)v;
        }
    }
    __shared__ double sh[TPB];
    sh[threadIdx.x] = acc;
    __syncthreads();
    for (int off = TPB / 2; off > 0; off >>= 1) {
        if (threadIdx.x < off) sh[threadIdx.x] += sh[threadIdx.x + off];
        __syncthreads();
    }
    if (threadIdx.x == 0) atomicAdd(&st->sum_gt[row], sh[0]);
}

__global__ void k_final(const SelState* __restrict__ st, float* __restrict__ out,
                        unsigned int n) {
    if (threadIdx.x == 0 && blockIdx.x == 0) {
        double tot = 0.0;
        for (int r = 0; r < ROWS; ++r)
            tot += st->sum_gt[r] + (double)st->krem[r] * (double)__uint_as_float(st->tau[r]);
        out[0] = (float)(tot / ((double)ROWS * (double)n));
    }
}

// =====================================================================

extern "C" void kernel_launch(void* const* d_in, const int* in_sizes, int n_in,
                              void* d_out, int out_size, void* d_ws, size_t ws_size,
                              hipStream_t stream) {
    const float* x  = (const float*)d_in[0];
    const float* tg = (const float*)d_in[1];
    float* out = (float*)d_out;

    const int total = in_sizes[0];
    const int N     = total / ROWS;                       // 2,097,152
    unsigned int n  = (unsigned int)llround((double)N * 0.10);
    if (n < 1) n = 1;

    const float4* x4 = (const float4*)x;
    const float4* t4 = (const float4*)tg;
    dim3 b(TPB);

    if (ws_size >= (size_t)FIXED_END && n > 2u * SLACK && (N % (256 * 4 * TPB)) == 0) {
        // ---------- fast path: sample bracket + ONE full pass ----------
        StateS* st = (StateS*)d_ws;
        unsigned int* sampleHist = (unsigned int*)((char*)d_ws + OFF_SAMPLE);

        hipMemsetAsync(d_ws, 0, FIXED_END, stream);
        k_sample<<<dim3(ROWS * 32), b, 0, stream>>>(x4, t4, sampleHist, N);
        k_range<<<dim3(ROWS), b, 0, stream>>>(sampleHist, st, n);
        k_mainsum<<<dim3(ROWS * 256), b, 0, stream>>>(x4, t4, st, N);
        k_fin<<<dim3(1), dim3(64), 0, stream>>>(st, sampleHist, out, n);
    } else {
        // ---------- fallback: proven exact 3-pass radix + sum ----------
        unsigned int* hist = (unsigned int*)d_ws;
        SelState* st = (SelState*)((char*)d_ws + (size_t)ROWS * FBINS * sizeof(unsigned int));
        dim3 gBig(ROWS * 128);
        k_init<<<dim3(1), b, 0, stream>>>(hist, st, n);
        k_hist<<<gBig, b, 0, stream>>>(x4, t4, hist, st, N, 0x00000000u, 21, 2047u);
        k_select<<<dim3(ROWS), b, 0, stream>>>(hist, st, 21, 2048, 0);
        k_hist<<<gBig, b, 0, stream>>>(x4, t4, hist, st, N, 0xFFE00000u, 10, 2047u);
        k_select<<<dim3(ROWS), b, 0, stream>>>(hist, st, 10, 2048, 0);
        k_hist<<<gBig, b, 0, stream>>>(x4, t4, hist, st, N, 0xFFFFFC00u, 0, 1023u);
        k_select<<<dim3(ROWS), b, 0, stream>>>(hist, st, 0, 1024, 1);
        k_sum<<<gBig, b, 0, stream>>>(x4, t4, st, N);
        k_final<<<dim3(1), dim3(64), 0, stream>>>(st, out, n);
    }
}